// Round 10
// baseline (762.867 us; speedup 1.0000x reference)
//
#include <hip/hip_runtime.h>
#include <hip/hip_bf16.h>
#include <cstdint>
#include <cstddef>

// Problem constants (match reference)
#define TOKENS 8192        // B*S
#define ASSIGN 16384       // TOKENS * TOPK
#define DM     512         // D_MODEL
#define DFF    2048        // D_FF
#define NEXP   64          // NCAT * NSUB
#define NSUB_  8
#define CAP2   512         // per-expert capacity region (counts ~256 +/- 16)
#define BK     64
#define BMT    128         // M-tile: 4 per expert, culled vs count (work cut 1.5x -> 1.25x)
#define BNT    256         // N-tile: 8 waves = 2 wm x 4 wn, 64x64 out each

typedef __bf16 bf16;
typedef __bf16 bf16x4 __attribute__((ext_vector_type(4)));
typedef __bf16 bf16x8 __attribute__((ext_vector_type(8)));
typedef float  f32x4  __attribute__((ext_vector_type(4)));

// ---------------- routing ----------------
__global__ void k_zero(int* __restrict__ count) { count[threadIdx.x] = 0; }

__global__ void k_route(const int* __restrict__ cat, const int* __restrict__ sub,
                        int* __restrict__ count, int* __restrict__ slot_of) {
    int a = blockIdx.x * 256 + threadIdx.x;
    if (a >= ASSIGN) return;
    int e = cat[a] * NSUB_ + sub[a];
    int s = atomicAdd(&count[e], 1);
    slot_of[a] = (s < CAP2) ? (e * CAP2 + s) : -1;   // order-invariant vs reference
}

// ---------------- gather x -> bf16 capacity buffer (4 assignments/block) ----------
__global__ void k_gather(const float* __restrict__ hidden, const int* __restrict__ slot_of,
                         bf16* __restrict__ xg) {
    int a = blockIdx.x * 4 + (threadIdx.x >> 6);
    int t = threadIdx.x & 63;
    int r = slot_of[a];
    if (r < 0) return;
    int tok = a >> 1;                 // TOPK = 2
    const f32x4* src = (const f32x4*)(hidden + (size_t)tok * DM);
    f32x4 v0 = src[t * 2], v1 = src[t * 2 + 1];
    bf16x8 o;
    o[0] = (bf16)v0[0]; o[1] = (bf16)v0[1]; o[2] = (bf16)v0[2]; o[3] = (bf16)v0[3];
    o[4] = (bf16)v1[0]; o[5] = (bf16)v1[1]; o[6] = (bf16)v1[2]; o[7] = (bf16)v1[3];
    *(bf16x8*)(xg + (size_t)r * DM + t * 8) = o;
}

// Cheap overflow-safe tanh-GELU (|err| vs exact ~3e-4; threshold 8.4e-2).
__device__ inline float gelu_tanh(float x) {
    float s2 = 1.5957691216057308f * x * (1.0f + 0.044715f * x * x);
    float z = __expf(-fabsf(s2));
    float sig = 1.0f / (1.0f + z);
    return (s2 >= 0.0f) ? x * sig : x * (1.0f - sig);
}

// ---------------- fused GEMM: R7-proven 2-barrier loop, BM=128 x BN=256 ----------
__device__ inline void gload_lds16(const void* g, void* l) {
    __builtin_amdgcn_global_load_lds((const __attribute__((address_space(1))) void*)g,
                                     (__attribute__((address_space(3))) void*)l, 16, 0, 0);
}

// A: [NEXP*CAP2][K] bf16 K-contig (global_load_lds, T2 swizzle, single buffer).
// W: [NEXP][K][N] fp32 -> reg transpose+convert -> Bs [256n][64k] bf16 swizzled.
// C[E*CAP2][N] = act(A*W + bias).  BM=128, BN=256, 8 waves (2x4), 48 KB LDS
// -> 2-3 blocks/CU cross-block overlap (m114) — the measured-best schedule (R7).
// 4 M-tiles/expert culled against count[e]: computes ~320 rows for ~256 live (was 384).
// 1-D grid, chunked-XCD decode, mtile fastest (W-panel mt group shares an XCD's L2).
template <bool GELU>
__global__ __launch_bounds__(512, 4)
void k_gemm(const bf16* __restrict__ A, const float* __restrict__ W,
            const float* __restrict__ bias, bf16* __restrict__ C,
            const int* __restrict__ count, int N, int K, int ntn) {
    __shared__ __align__(16) char As[BMT * 128];    // 16 KB: 128 rows x 64 k bf16, swizzled
    __shared__ __align__(16) char Bs[BNT * 128];    // 32 KB: 256 n x 64 k bf16, swizzled

    // chunked XCD swizzle: consecutive logical ids share an XCD.
    int nwg = gridDim.x;                            // multiple of 8
    int lg = (int)(blockIdx.x & 7) * (nwg >> 3) + (int)(blockIdx.x >> 3);
    int e = lg / (4 * ntn);
    int rem = lg - e * 4 * ntn;
    int ntile = rem >> 2, mtile = rem & 3;          // mtile fastest: mt group same XCD

    int mc = count[e]; if (mc > CAP2) mc = CAP2;
    if (mtile * BMT >= mc) return;                  // cull dead M-tile
    int tid = threadIdx.x, wave = tid >> 6, lane = tid & 63;
    int wm = wave >> 2, wn = wave & 3;              // 2x4 waves, 64x64 out each

    const char*  Ag = (const char*)(A + (size_t)(e * CAP2 + mtile * BMT) * K);
    const float* Wg = W + (size_t)e * K * N + (size_t)ntile * BNT;

    // B-staging: kq in [0,16) k-groups of 4; nq in [0,64) n-groups of 4 (2 slots/thread).
    int kq = ((lane >> 3) & 7) | ((wave & 1) << 3);

    f32x4 br[2][4];
    auto issueB = [&](int kt) {                     // 8 global_load_dwordx4 (256 B/thread)
#pragma unroll
        for (int s = 0; s < 2; s++) {
            int nq = (lane & 7) + 8 * (((wave >> 1) & 3) + 4 * s);
            const float* p = Wg + (size_t)(kt * BK + kq * 4) * N + nq * 4;
            br[s][0] = *(const f32x4*)(p);
            br[s][1] = *(const f32x4*)(p + N);
            br[s][2] = *(const f32x4*)(p + 2 * (size_t)N);
            br[s][3] = *(const f32x4*)(p + 3 * (size_t)N);
        }
    };
    auto writeB = [&]() {                           // reg transpose+convert -> swizzled LDS
#pragma unroll
        for (int s = 0; s < 2; s++) {
            int nq = (lane & 7) + 8 * (((wave >> 1) & 3) + 4 * s);
#pragma unroll
            for (int c = 0; c < 4; c++) {
                int n = nq * 4 + c;
                bf16x4 v;
#pragma unroll
                for (int j = 0; j < 4; j++) v[j] = (bf16)br[s][j][c];
                *(bf16x4*)(Bs + n * 128 + ((kq * 8) ^ ((n & 7) << 4))) = v;
            }
        }
    };
    auto issueA = [&](int kt) {                     // 16 KB: 2 gload_lds/thread
#pragma unroll
        for (int i = 0; i < 2; i++) {
            int chunk = i * 8 + wave;
            int d = chunk * 1024 + lane * 16;       // linear dest byte
            int row = d >> 7;                       // 128 B per LDS row
            int col = (d & 127) ^ ((row & 7) << 4); // pre-swizzled SOURCE (rule #21)
            gload_lds16(Ag + (size_t)row * (2 * K) + (size_t)kt * 128 + col,
                        As + chunk * 1024);
        }
    };

    f32x4 acc[4][4];
#pragma unroll
    for (int i = 0; i < 4; i++)
#pragma unroll
        for (int j = 0; j < 4; j++) acc[i][j] = f32x4{0.f, 0.f, 0.f, 0.f};

    issueB(0);
    int nK = K >> 6;
    for (int kt = 0; kt < nK; kt++) {
        issueA(kt);
        asm volatile("s_waitcnt vmcnt(0)" ::: "memory");   // A(kt) in LDS, B(kt) in regs
        writeB();
        if (kt + 1 < nK) issueB(kt + 1);                   // prefetch across MFMA phase
        asm volatile("s_waitcnt lgkmcnt(0)" ::: "memory");
        __builtin_amdgcn_s_barrier();                      // raw: B(kt+1) stays in flight
        __builtin_amdgcn_sched_barrier(0);
#pragma unroll
        for (int ks = 0; ks < 2; ks++) {
            bf16x8 af[4], bfv[4];
#pragma unroll
            for (int mi = 0; mi < 4; mi++) {
                int row = wm * 64 + mi * 16 + (lane & 15);
                af[mi] = *(const bf16x8*)(As + row * 128 +
                         ((ks * 64 + (lane >> 4) * 16) ^ ((row & 7) << 4)));
            }
#pragma unroll
            for (int ni = 0; ni < 4; ni++) {
                int nn = wn * 64 + ni * 16 + (lane & 15);
                bfv[ni] = *(const bf16x8*)(Bs + nn * 128 +
                          ((ks * 64 + (lane >> 4) * 16) ^ ((nn & 7) << 4)));
            }
#pragma unroll
            for (int mi = 0; mi < 4; mi++)
#pragma unroll
                for (int ni = 0; ni < 4; ni++)
                    acc[mi][ni] = __builtin_amdgcn_mfma_f32_16x16x32_bf16(
                        af[mi], bfv[ni], acc[mi][ni], 0, 0, 0);
        }
        __builtin_amdgcn_sched_barrier(0);
        __builtin_amdgcn_s_barrier();                      // all reads done before restage
    }

    // epilogue: bias + (optional) tanh-GELU, write bf16
#pragma unroll
    for (int mi = 0; mi < 4; mi++) {
        int rowb = wm * 64 + mi * 16 + ((lane >> 4) << 2);
#pragma unroll
        for (int ni = 0; ni < 4; ni++) {
            int col = ntile * BNT + wn * 64 + ni * 16 + (lane & 15);
            float bv = bias[e * N + col];
#pragma unroll
            for (int r = 0; r < 4; r++) {
                float v = acc[mi][ni][r] + bv;
                if (GELU) v = gelu_tanh(v);
                int grow = e * CAP2 + mtile * BMT + rowb + r;
                C[(size_t)grow * N + col] = (bf16)v;
            }
        }
    }
}

// ---------------- combine (4 tokens/block) ----------------
__global__ void k_combine(const float* __restrict__ wts, const int* __restrict__ slot_of,
                          const bf16* __restrict__ y, float* __restrict__ out) {
    int tok = blockIdx.x * 4 + (threadIdx.x >> 6);
    int t = threadIdx.x & 63;
    float acc[8] = {0, 0, 0, 0, 0, 0, 0, 0};
#pragma unroll
    for (int k = 0; k < 2; k++) {
        int a = tok * 2 + k;
        int r = slot_of[a];
        if (r >= 0) {
            float w = wts[a];
            bf16x8 v = *(const bf16x8*)(y + (size_t)r * DM + t * 8);
#pragma unroll
            for (int j = 0; j < 8; j++) acc[j] += w * (float)v[j];
        }
    }
    f32x4* o = (f32x4*)(out + (size_t)tok * DM + t * 8);
    o[0] = f32x4{acc[0], acc[1], acc[2], acc[3]};
    o[1] = f32x4{acc[4], acc[5], acc[6], acc[7]};
}

// ---------------- launch ----------------
extern "C" void kernel_launch(void* const* d_in, const int* in_sizes, int n_in,
                              void* d_out, int out_size, void* d_ws, size_t ws_size,
                              hipStream_t stream) {
    const float* hidden = (const float*)d_in[0];
    const int*   cat    = (const int*)d_in[1];
    const int*   sub    = (const int*)d_in[2];
    const float* wts    = (const float*)d_in[3];
    const float* W1     = (const float*)d_in[4];
    const float* b1     = (const float*)d_in[5];
    const float* W2     = (const float*)d_in[6];
    const float* b2     = (const float*)d_in[7];
    float* out = (float*)d_out;

    // workspace (~168 MB): hbuf bf16 [E*CAP2][DFF], xg/y aliased bf16 [E*CAP2][DM]
    char* ws = (char*)d_ws;
    size_t off = 0;
    bf16* hbuf = (bf16*)(ws + off); off += (size_t)NEXP * CAP2 * DFF * 2;
    bf16* xg   = (bf16*)(ws + off); off += (size_t)NEXP * CAP2 * DM * 2;
    bf16* y    = xg;  // xg dead after GEMM1; GEMM2 writes y here (stream-ordered)
    int* count   = (int*)(ws + off); off += 256;
    int* slot_of = (int*)(ws + off); off += (size_t)ASSIGN * 4;

    k_zero<<<1, 64, 0, stream>>>(count);
    k_route<<<ASSIGN / 256, 256, 0, stream>>>(cat, sub, count, slot_of);
    k_gather<<<ASSIGN / 4, 256, 0, stream>>>(hidden, slot_of, xg);

    // h = gelu(x @ W1 + b1): N=2048, K=512.  grid 64e x 8nt x 4mt = 2048 (1-D, %8==0)
    k_gemm<true><<<dim3(NEXP * 8 * 4), 512, 0, stream>>>(
        xg, W1, b1, hbuf, count, DFF, DM, 8);

    // y = h @ W2 + b2: N=512, K=2048.  grid 64e x 2nt x 4mt = 512 (1-D, %8==0)
    k_gemm<false><<<dim3(NEXP * 2 * 4), 512, 0, stream>>>(
        hbuf, W2, b2, y, count, DM, DFF, 2);

    k_combine<<<TOKENS / 4, 256, 0, stream>>>(wts, slot_of, y, out);
}

// Round 11
// 294.675 us; speedup vs baseline: 2.5888x; 2.5888x over previous
//
#include <hip/hip_runtime.h>
#include <hip/hip_bf16.h>
#include <cstdint>
#include <cstddef>

// Problem constants (match reference)
#define TOKENS 8192        // B*S
#define ASSIGN 16384       // TOKENS * TOPK
#define DM     512         // D_MODEL
#define DFF    2048        // D_FF
#define NEXP   64          // NCAT * NSUB
#define NSUB_  8
#define CAP2   512         // per-expert capacity region (counts ~256 +/- 16)
#define BK     64
#define BMT    256         // GEMM M-tile (8 waves, 4x2, 64x64 each)

typedef __bf16 bf16;
typedef __bf16 bf16x4 __attribute__((ext_vector_type(4)));
typedef __bf16 bf16x8 __attribute__((ext_vector_type(8)));
typedef float  f32x4  __attribute__((ext_vector_type(4)));

// ---------------- routing ----------------
__global__ void k_route(const int* __restrict__ cat, const int* __restrict__ sub,
                        int* __restrict__ count, int* __restrict__ slot_of) {
    int a = blockIdx.x * 256 + threadIdx.x;
    if (a >= ASSIGN) return;
    int e = cat[a] * NSUB_ + sub[a];
    int s = atomicAdd(&count[e], 1);
    slot_of[a] = (s < CAP2) ? (e * CAP2 + s) : -1;   // order-invariant vs reference
}

// ---------------- gather x -> bf16 capacity buffer (4 assignments/block) ----------
__global__ void k_gather(const float* __restrict__ hidden, const int* __restrict__ slot_of,
                         bf16* __restrict__ xg) {
    int a = blockIdx.x * 4 + (threadIdx.x >> 6);
    int t = threadIdx.x & 63;
    int r = slot_of[a];
    if (r < 0) return;
    int tok = a >> 1;                 // TOPK = 2
    const f32x4* src = (const f32x4*)(hidden + (size_t)tok * DM);
    f32x4 v0 = src[t * 2], v1 = src[t * 2 + 1];
    bf16x8 o;
    o[0] = (bf16)v0[0]; o[1] = (bf16)v0[1]; o[2] = (bf16)v0[2]; o[3] = (bf16)v0[3];
    o[4] = (bf16)v1[0]; o[5] = (bf16)v1[1]; o[6] = (bf16)v1[2]; o[7] = (bf16)v1[3];
    *(bf16x8*)(xg + (size_t)r * DM + t * 8) = o;
}

// Cheap overflow-safe tanh-GELU (|err| vs exact erf-GELU ~3e-4; threshold 8.4e-2).
// Measured safe in R8 (absmax 0.031); cuts epilogue VALU (VALUBusy 32% -> 26%).
__device__ inline float gelu_tanh(float x) {
    float s2 = 1.5957691216057308f * x * (1.0f + 0.044715f * x * x);
    float z = __expf(-fabsf(s2));
    float sig = 1.0f / (1.0f + z);
    return (s2 >= 0.0f) ? x * sig : x * (1.0f - sig);
}

// ---------------- fused GEMM: R7 measured-best (total 307 us) -------------------
__device__ inline void gload_lds16(const void* g, void* l) {
    __builtin_amdgcn_global_load_lds((const __attribute__((address_space(1))) void*)g,
                                     (__attribute__((address_space(3))) void*)l, 16, 0, 0);
}

// A: [NEXP*CAP2][K] bf16 K-contig (global_load_lds, T2 swizzle, single buffer).
// W: [NEXP][K][N] fp32 -> reg transpose+convert -> Bs [128n][64k] bf16 swizzled.
// C[E*CAP2][N] = act(A*W + bias).  BM=256, BN=128, 8 waves (4x2), 48 KB LDS
// -> 2-3 blocks/CU: cross-block overlap hides the per-iter drain (m114 mechanism).
// 1-D grid, chunked-XCD decode, mtile fastest (W-panel mt pair shares an XCD's L2:
// measured FETCH 143 MB ~= W1 read once from HBM).
template <bool GELU>
__global__ __launch_bounds__(512, 4)
void k_gemm(const bf16* __restrict__ A, const float* __restrict__ W,
            const float* __restrict__ bias, bf16* __restrict__ C,
            const int* __restrict__ count, int N, int K, int ntn) {
    __shared__ __align__(16) char As[BMT * 128];    // 32 KB: 256 rows x 64 k bf16, swizzled
    __shared__ __align__(16) char Bs[128 * 128];    // 16 KB: 128 n x 64 k bf16, swizzled

    // chunked XCD swizzle: consecutive logical ids share an XCD.
    int nwg = gridDim.x;                            // multiple of 8
    int lg = (int)(blockIdx.x & 7) * (nwg >> 3) + (int)(blockIdx.x >> 3);
    int e = lg / (2 * ntn);
    int rem = lg - e * 2 * ntn;
    int ntile = rem >> 1, mtile = rem & 1;          // mtile fastest: W-panel pair same XCD

    int mc = count[e]; if (mc > CAP2) mc = CAP2;
    if (mtile * BMT >= mc) return;                  // dead M-tile (counts ~256: mt1 ~dead)
    int tid = threadIdx.x, wave = tid >> 6, lane = tid & 63;
    int wm = wave >> 1, wn = wave & 1;              // 4x2 waves, 64x64 out each

    const char*  Ag = (const char*)(A + (size_t)(e * CAP2 + mtile * BMT) * K);
    const float* Wg = W + (size_t)e * K * N + (size_t)ntile * 128;

    // B-staging mapping: kq in [0,16) k-groups of 4; nq in [0,32) n-groups of 4.
    int kq = ((lane >> 3) & 7) | ((wave & 1) << 3);
    int nq = (lane & 7) | (((wave >> 1) & 3) << 3);

    f32x4 br[4];
    auto issueB = [&](int kt) {                     // 4 global_load_dwordx4 (128 B/thread)
        const float* p = Wg + (size_t)(kt * BK + kq * 4) * N + nq * 4;
        br[0] = *(const f32x4*)(p);
        br[1] = *(const f32x4*)(p + N);
        br[2] = *(const f32x4*)(p + 2 * (size_t)N);
        br[3] = *(const f32x4*)(p + 3 * (size_t)N);
    };
    auto writeB = [&]() {                           // reg transpose+convert -> swizzled LDS
#pragma unroll
        for (int c = 0; c < 4; c++) {
            int n = nq * 4 + c;
            bf16x4 v;
#pragma unroll
            for (int j = 0; j < 4; j++) v[j] = (bf16)br[j][c];
            *(bf16x4*)(Bs + n * 128 + ((kq * 8) ^ ((n & 7) << 4))) = v;
        }
    };
    auto issueA = [&](int kt) {                     // 32 KB: 4 gload_lds/thread
#pragma unroll
        for (int i = 0; i < 4; i++) {
            int chunk = i * 8 + wave;
            int d = chunk * 1024 + lane * 16;       // linear dest byte
            int row = d >> 7;                       // 128 B per LDS row
            int col = (d & 127) ^ ((row & 7) << 4); // pre-swizzled SOURCE (rule #21)
            gload_lds16(Ag + (size_t)row * (2 * K) + (size_t)kt * 128 + col,
                        As + chunk * 1024);
        }
    };

    f32x4 acc[4][4];
#pragma unroll
    for (int i = 0; i < 4; i++)
#pragma unroll
        for (int j = 0; j < 4; j++) acc[i][j] = f32x4{0.f, 0.f, 0.f, 0.f};

    issueB(0);
    int nK = K >> 6;
    for (int kt = 0; kt < nK; kt++) {
        issueA(kt);
        asm volatile("s_waitcnt vmcnt(0)" ::: "memory");   // A(kt) in LDS, B(kt) in regs
        writeB();
        if (kt + 1 < nK) issueB(kt + 1);                   // prefetch across MFMA phase
        asm volatile("s_waitcnt lgkmcnt(0)" ::: "memory");
        __builtin_amdgcn_s_barrier();                      // raw: B(kt+1) stays in flight
        __builtin_amdgcn_sched_barrier(0);
#pragma unroll
        for (int ks = 0; ks < 2; ks++) {
            bf16x8 af[4], bfv[4];
#pragma unroll
            for (int mi = 0; mi < 4; mi++) {
                int row = wm * 64 + mi * 16 + (lane & 15);
                af[mi] = *(const bf16x8*)(As + row * 128 +
                         ((ks * 64 + (lane >> 4) * 16) ^ ((row & 7) << 4)));
            }
#pragma unroll
            for (int ni = 0; ni < 4; ni++) {
                int n = wn * 64 + ni * 16 + (lane & 15);
                bfv[ni] = *(const bf16x8*)(Bs + n * 128 +
                          ((ks * 64 + (lane >> 4) * 16) ^ ((n & 7) << 4)));
            }
#pragma unroll
            for (int mi = 0; mi < 4; mi++)
#pragma unroll
                for (int ni = 0; ni < 4; ni++)
                    acc[mi][ni] = __builtin_amdgcn_mfma_f32_16x16x32_bf16(
                        af[mi], bfv[ni], acc[mi][ni], 0, 0, 0);
        }
        __builtin_amdgcn_sched_barrier(0);
        __builtin_amdgcn_s_barrier();                      // all reads done before restage
    }

    // epilogue: bias + (optional) tanh-GELU, write bf16
#pragma unroll
    for (int mi = 0; mi < 4; mi++) {
        int rowb = wm * 64 + mi * 16 + ((lane >> 4) << 2);
#pragma unroll
        for (int ni = 0; ni < 4; ni++) {
            int col = ntile * 128 + wn * 64 + ni * 16 + (lane & 15);
            float bv = bias[e * N + col];
#pragma unroll
            for (int r = 0; r < 4; r++) {
                float v = acc[mi][ni][r] + bv;
                if (GELU) v = gelu_tanh(v);
                int grow = e * CAP2 + mtile * BMT + rowb + r;
                C[(size_t)grow * N + col] = (bf16)v;
            }
        }
    }
}

// ---------------- combine (4 tokens/block) ----------------
__global__ void k_combine(const float* __restrict__ wts, const int* __restrict__ slot_of,
                          const bf16* __restrict__ y, float* __restrict__ out) {
    int tok = blockIdx.x * 4 + (threadIdx.x >> 6);
    int t = threadIdx.x & 63;
    float acc[8] = {0, 0, 0, 0, 0, 0, 0, 0};
#pragma unroll
    for (int k = 0; k < 2; k++) {
        int a = tok * 2 + k;
        int r = slot_of[a];
        if (r >= 0) {
            float w = wts[a];
            bf16x8 v = *(const bf16x8*)(y + (size_t)r * DM + t * 8);
#pragma unroll
            for (int j = 0; j < 8; j++) acc[j] += w * (float)v[j];
        }
    }
    f32x4* o = (f32x4*)(out + (size_t)tok * DM + t * 8);
    o[0] = f32x4{acc[0], acc[1], acc[2], acc[3]};
    o[1] = f32x4{acc[4], acc[5], acc[6], acc[7]};
}

// ---------------- launch ----------------
extern "C" void kernel_launch(void* const* d_in, const int* in_sizes, int n_in,
                              void* d_out, int out_size, void* d_ws, size_t ws_size,
                              hipStream_t stream) {
    const float* hidden = (const float*)d_in[0];
    const int*   cat    = (const int*)d_in[1];
    const int*   sub    = (const int*)d_in[2];
    const float* wts    = (const float*)d_in[3];
    const float* W1     = (const float*)d_in[4];
    const float* b1     = (const float*)d_in[5];
    const float* W2     = (const float*)d_in[6];
    const float* b2     = (const float*)d_in[7];
    float* out = (float*)d_out;

    // workspace (~168 MB): hbuf bf16 [E*CAP2][DFF], xg/y aliased bf16 [E*CAP2][DM]
    char* ws = (char*)d_ws;
    size_t off = 0;
    bf16* hbuf = (bf16*)(ws + off); off += (size_t)NEXP * CAP2 * DFF * 2;
    bf16* xg   = (bf16*)(ws + off); off += (size_t)NEXP * CAP2 * DM * 2;
    bf16* y    = xg;  // xg dead after GEMM1; GEMM2 writes y here (stream-ordered)
    int* count   = (int*)(ws + off); off += 256;
    int* slot_of = (int*)(ws + off); off += (size_t)ASSIGN * 4;

    hipMemsetAsync(count, 0, 256, stream);      // graph-capturable memset node
    k_route<<<ASSIGN / 256, 256, 0, stream>>>(cat, sub, count, slot_of);
    k_gather<<<ASSIGN / 4, 256, 0, stream>>>(hidden, slot_of, xg);

    // h = gelu(x @ W1 + b1): N=2048, K=512.  grid 64e x 16nt x 2mt = 2048 (1-D, %8==0)
    k_gemm<true><<<dim3(NEXP * 16 * 2), 512, 0, stream>>>(
        xg, W1, b1, hbuf, count, DFF, DM, 16);

    // y = h @ W2 + b2: N=512, K=2048.  grid 64e x 4nt x 2mt = 512 (1-D, %8==0)
    k_gemm<false><<<dim3(NEXP * 4 * 2), 512, 0, stream>>>(
        hbuf, W2, b2, y, count, DM, DFF, 4);

    k_combine<<<TOKENS / 4, 256, 0, stream>>>(wts, slot_of, y, out);
}